// Round 8
// baseline (895.758 us; speedup 1.0000x reference)
//
#include <hip/hip_runtime.h>
#include <hip/hip_bf16.h>

typedef _Float16 half4v __attribute__((ext_vector_type(4)));
typedef _Float16 half8v __attribute__((ext_vector_type(8)));
typedef float float4v __attribute__((ext_vector_type(4)));
typedef float float16v __attribute__((ext_vector_type(16)));

#define L_SEQ 2048
#define EMB 1024
#define NH 16
#define DKV 64

__device__ inline void gll16(const void* g, void* l) {
  __builtin_amdgcn_global_load_lds((const __attribute__((address_space(1))) void*)g,
                                   (__attribute__((address_space(3))) void*)l, 16, 0, 0);
}

// ---------------------------------------------------------------------------
// Kernel A: cast X fp32 -> f16 (4096x1024), 8 elems/thread
// ---------------------------------------------------------------------------
__global__ __launch_bounds__(256) void xcast_kernel(const float* __restrict__ X,
                                                    _Float16* __restrict__ X16) {
  size_t i = ((size_t)blockIdx.x * 256 + threadIdx.x) * 8;
  float4v v0 = *(const float4v*)(X + i);
  float4v v1 = *(const float4v*)(X + i + 4);
  half8v h;
  h[0] = (_Float16)v0[0]; h[1] = (_Float16)v0[1]; h[2] = (_Float16)v0[2]; h[3] = (_Float16)v0[3];
  h[4] = (_Float16)v1[0]; h[5] = (_Float16)v1[1]; h[6] = (_Float16)v1[2]; h[7] = (_Float16)v1[3];
  *(half8v*)(X16 + i) = h;
}

// ---------------------------------------------------------------------------
// Kernel B: pack + transpose + cast W_qkv (fp32 [1024][3072]) -> Wt (f16 [2048][1024])
// ---------------------------------------------------------------------------
__global__ __launch_bounds__(256) void wpack_kernel(const float* __restrict__ W,
                                                    _Float16* __restrict__ Wt) {
  __shared__ float tile[32][33];
  int n0 = blockIdx.x * 32;
  int k0 = blockIdx.y * 32;
  int h = n0 >> 7;
  int wc = h * 192 + (n0 & 127);
  int tx = threadIdx.x & 31;
  int ty = threadIdx.x >> 5;
#pragma unroll
  for (int i = 0; i < 4; ++i) {
    int k = ty + i * 8;
    tile[k][tx] = W[(size_t)(k0 + k) * 3072 + wc + tx];
  }
  __syncthreads();
#pragma unroll
  for (int i = 0; i < 4; ++i) {
    int n = ty + i * 8;
    Wt[(size_t)(n0 + n) * 1024 + k0 + tx] = (_Float16)tile[tx][n];
  }
}

// ---------------------------------------------------------------------------
// Kernel C (v2): Q/K projection GEMM. BM=128, BN=64, BK=32 -> 1024 blocks
// (4/CU, fixes 2-block/CU grid starvation). DIAGNOSTIC: blockIdx.z = 16
// replicas writing identical values; surfaces in top-5 with counters.
// ---------------------------------------------------------------------------
__global__ __launch_bounds__(256, 4) void qk_gemm_kernel(const _Float16* __restrict__ X16,
                                                         const _Float16* __restrict__ Wt,
                                                         const float* __restrict__ bias,
                                                         _Float16* __restrict__ Qh,
                                                         _Float16* __restrict__ Kh) {
  __shared__ _Float16 As[128 * 32];
  __shared__ _Float16 Bs[64 * 32];
  int n0 = blockIdx.x * 64;
  int m0 = blockIdx.y * 128;
  int t = threadIdx.x;
  int l = t & 63;
  int wv = t >> 6;
  int wm = wv >> 1, wn = wv & 1;
  int cl = l & 15, ko = (l >> 4) * 8;
  int srow = (l >> 2);      // 0..15 within a 16-row chunk
  int scol = (l & 3) * 8;   // f16 col offset
  float4v acc[4][2] = {};
  for (int k0 = 0; k0 < 1024; k0 += 32) {
#pragma unroll
    for (int c = 0; c < 2; ++c) {
      int rbase = wv * 32 + c * 16;
      gll16(X16 + (size_t)(m0 + rbase + srow) * 1024 + k0 + scol, &As[rbase * 32]);
    }
    gll16(Wt + (size_t)(n0 + wv * 16 + srow) * 1024 + k0 + scol, &Bs[wv * 16 * 32]);
    __syncthreads();
    half8v a[4], b[2];
#pragma unroll
    for (int mt = 0; mt < 4; ++mt) a[mt] = *(const half8v*)(&As[(wm * 64 + mt * 16 + cl) * 32 + ko]);
#pragma unroll
    for (int nt = 0; nt < 2; ++nt) b[nt] = *(const half8v*)(&Bs[(wn * 32 + nt * 16 + cl) * 32 + ko]);
#pragma unroll
    for (int mt = 0; mt < 4; ++mt)
#pragma unroll
      for (int nt = 0; nt < 2; ++nt)
        acc[mt][nt] = __builtin_amdgcn_mfma_f32_16x16x32_f16(a[mt], b[nt], acc[mt][nt], 0, 0, 0);
    __syncthreads();
  }
#pragma unroll
  for (int mt = 0; mt < 4; ++mt) {
#pragma unroll
    for (int nt = 0; nt < 2; ++nt) {
      int n_g = n0 + wn * 32 + nt * 16 + cl;
      int hh = n_g >> 7, rr = n_g & 127;
      float bv = bias[hh * 192 + rr];
      _Float16* dstbase = (rr < 64) ? Qh : Kh;
      int d = rr & 63;
#pragma unroll
      for (int r = 0; r < 4; ++r) {
        int row_g = m0 + wm * 64 + mt * 16 + (l >> 4) * 4 + r;
        int bb = row_g >> 11, lr = row_g & 2047;
        dstbase[(((size_t)bb * NH + hh) * L_SEQ + lr) * DKV + d] = (_Float16)(acc[mt][nt][r] + bv);
      }
    }
  }
}

// ---------------------------------------------------------------------------
// Kernel D (v6 structure, x4 replicas): S = Q K^T / 8, softmax, write fp32.
// LDS-staged K (global_load_lds dbuf, XOR-swizzled granules), 128-j steps,
// dual-orientation 32x32x16 MFMA passes, normalization folded into exponent,
// nontemporal direct line stores. DIAGNOSTIC: grid 4096 = 4 identical
// replicas (benign same-value writes) to surface in rocprof top-5.
// ---------------------------------------------------------------------------
__global__ __launch_bounds__(256, 4) void attn_softmax_kernel(const _Float16* __restrict__ Qh,
                                                              const _Float16* __restrict__ Kh,
                                                              float* __restrict__ out) {
  __shared__ _Float16 Ks[2][128 * 64];  // 32 KB dbuf, granule-swizzled rows
  __shared__ float sums[4][32];
  int id = blockIdx.x & 1023;  // replicas: blockIdx.x>>10 in {0..3}
  int xcd = id & 7;
  int rest = id >> 3;
  int rb = rest & 31;
  int bh = ((rest >> 5) << 3) + xcd;  // bijective XCD swizzle
  int t = threadIdx.x;
  int l = t & 63;
  int wv = t >> 6;
  int lj = l & 31;   // 32-lane index (q-col in pass1 / j-col in pass2)
  int hk = l >> 5;   // k-half
  int qh = wv & 1;   // q-half owned by this wave
  int jh = wv >> 1;  // j-half of each 128-step
  int qbase = rb * 64;
  const _Float16* Qb = Qh + ((size_t)bh * L_SEQ + qbase) * DKV;
  const _Float16* Kb = Kh + (size_t)bh * L_SEQ * DKV;
  const float SC = 0.18033688011112042f;  // log2(e)/sqrt(64)

  half8v bq[4];
#pragma unroll
  for (int ks = 0; ks < 4; ++ks)
    bq[ks] = *(const half8v*)(Qb + (size_t)(qh * 32 + lj) * DKV + ks * 16 + hk * 8);

#define STAGE(bufi, j0)                                                     \
  {                                                                         \
    _Pragma("unroll") for (int c = 0; c < 4; ++c) {                         \
      int gi = (wv * 4 + c) * 64 + l;                                       \
      int r_ = gi >> 3, s_ = gi & 7;                                        \
      gll16(Kb + (size_t)((j0) + r_) * DKV + 8 * (s_ ^ (r_ & 7)),           \
            &Ks[bufi][(wv * 4 + c) * 512]);                                 \
    }                                                                       \
  }

  // ---- Pass 1: row sums.  mfma(A=K, B=Q): D col = q (lj), rows = j ----
  float lsum = 0.f;
  int buf = 0;
  STAGE(0, 0);
  __syncthreads();
  for (int s = 0; s < 16; ++s) {
    if (s + 1 < 16) STAGE(buf ^ 1, (s + 1) * 128);
#pragma unroll
    for (int q2 = 0; q2 < 2; ++q2) {
      int jq = jh * 2 + q2;
      int krow = jq * 32 + lj;
      half8v bk[4];
#pragma unroll
      for (int ks = 0; ks < 4; ++ks)
        bk[ks] = *(const half8v*)(&Ks[buf][krow * 64 + 8 * ((2 * ks + hk) ^ (krow & 7))]);
      float16v acc = {};
#pragma unroll
      for (int ks = 0; ks < 4; ++ks)
        acc = __builtin_amdgcn_mfma_f32_32x32x16_f16(bk[ks], bq[ks], acc, 0, 0, 0);
#pragma unroll
      for (int i = 0; i < 16; ++i) lsum += __builtin_amdgcn_exp2f(acc[i] * SC);
    }
    __syncthreads();
    buf ^= 1;
  }
  lsum += __shfl_xor(lsum, 32);
  if (l < 32) sums[wv][lj] = lsum;
  __syncthreads();

  float cc[16];
#pragma unroll
  for (int i = 0; i < 16; ++i) {
    int qo = (i & 3) + 8 * (i >> 2) + 4 * hk;
    cc[i] = -__log2f(sums[qh][qo] + sums[qh + 2][qo]);
  }

  // ---- Pass 2: recompute, mfma(A=Q, B=K): D col = j (lj), rows = q ----
  size_t orow0 = ((size_t)bh * L_SEQ + qbase + qh * 32) * L_SEQ;
  STAGE(0, 0);
  __syncthreads();
  buf = 0;
  for (int s = 0; s < 16; ++s) {
    if (s + 1 < 16) STAGE(buf ^ 1, (s + 1) * 128);
#pragma unroll
    for (int q2 = 0; q2 < 2; ++q2) {
      int jq = jh * 2 + q2;
      int krow = jq * 32 + lj;
      half8v bk[4];
#pragma unroll
      for (int ks = 0; ks < 4; ++ks)
        bk[ks] = *(const half8v*)(&Ks[buf][krow * 64 + 8 * ((2 * ks + hk) ^ (krow & 7))]);
      float16v acc = {};
#pragma unroll
      for (int ks = 0; ks < 4; ++ks)
        acc = __builtin_amdgcn_mfma_f32_32x32x16_f16(bq[ks], bk[ks], acc, 0, 0, 0);
      size_t col = (size_t)s * 128 + jq * 32 + lj;
#pragma unroll
      for (int i = 0; i < 16; ++i) {
        float p = __builtin_amdgcn_exp2f(acc[i] * SC + cc[i]);
        int qo = (i & 3) + 8 * (i >> 2) + 4 * hk;
        __builtin_nontemporal_store(p, out + orow0 + (size_t)qo * L_SEQ + col);
      }
    }
    __syncthreads();
    buf ^= 1;
  }
#undef STAGE
}

// ---------------------------------------------------------------------------
extern "C" void kernel_launch(void* const* d_in, const int* in_sizes, int n_in,
                              void* d_out, int out_size, void* d_ws, size_t ws_size,
                              hipStream_t stream) {
  const float* X = (const float*)d_in[0];
  const float* W = (const float*)d_in[1];
  const float* bias = (const float*)d_in[2];
  float* out = (float*)d_out;
  char* ws = (char*)d_ws;
  _Float16* Wt = (_Float16*)ws;                       // 4 MB
  _Float16* Qh = (_Float16*)(ws + (4ull << 20));      // 8 MB
  _Float16* Kh = (_Float16*)(ws + (12ull << 20));     // 8 MB
  _Float16* X16 = (_Float16*)(ws + (20ull << 20));    // 8 MB (total 28 MB)

  xcast_kernel<<<2048, 256, 0, stream>>>(X, X16);
  wpack_kernel<<<dim3(64, 32), 256, 0, stream>>>(W, Wt);
  // DIAGNOSTIC x16 replicas (blockIdx.z): identical writes, surfaces counters.
  qk_gemm_kernel<<<dim3(32, 32, 16), 256, 0, stream>>>(X16, Wt, bias, Qh, Kh);
  // DIAGNOSTIC x4 replicas: identical writes, surfaces counters.
  attn_softmax_kernel<<<4096, 256, 0, stream>>>(Qh, Kh, out);
}

// Round 9
// 160.390 us; speedup vs baseline: 5.5849x; 5.5849x over previous
//
#include <hip/hip_runtime.h>
#include <hip/hip_bf16.h>

typedef _Float16 half4v __attribute__((ext_vector_type(4)));
typedef _Float16 half8v __attribute__((ext_vector_type(8)));
typedef float float4v __attribute__((ext_vector_type(4)));
typedef float float16v __attribute__((ext_vector_type(16)));

#define L_SEQ 2048
#define EMB 1024
#define NH 16
#define DKV 64

__device__ inline void gll16(const void* g, void* l) {
  __builtin_amdgcn_global_load_lds((const __attribute__((address_space(1))) void*)g,
                                   (__attribute__((address_space(3))) void*)l, 16, 0, 0);
}

// ---------------------------------------------------------------------------
// Kernel A: cast X fp32 -> f16 (4096x1024), 8 elems/thread
// ---------------------------------------------------------------------------
__global__ __launch_bounds__(256) void xcast_kernel(const float* __restrict__ X,
                                                    _Float16* __restrict__ X16) {
  size_t i = ((size_t)blockIdx.x * 256 + threadIdx.x) * 8;
  float4v v0 = *(const float4v*)(X + i);
  float4v v1 = *(const float4v*)(X + i + 4);
  half8v h;
  h[0] = (_Float16)v0[0]; h[1] = (_Float16)v0[1]; h[2] = (_Float16)v0[2]; h[3] = (_Float16)v0[3];
  h[4] = (_Float16)v1[0]; h[5] = (_Float16)v1[1]; h[6] = (_Float16)v1[2]; h[7] = (_Float16)v1[3];
  *(half8v*)(X16 + i) = h;
}

// ---------------------------------------------------------------------------
// Kernel B: pack + transpose + cast W_qkv (fp32 [1024][3072]) -> Wt (f16 [2048][1024])
// ---------------------------------------------------------------------------
__global__ __launch_bounds__(256) void wpack_kernel(const float* __restrict__ W,
                                                    _Float16* __restrict__ Wt) {
  __shared__ float tile[32][33];
  int n0 = blockIdx.x * 32;
  int k0 = blockIdx.y * 32;
  int h = n0 >> 7;
  int wc = h * 192 + (n0 & 127);
  int tx = threadIdx.x & 31;
  int ty = threadIdx.x >> 5;
#pragma unroll
  for (int i = 0; i < 4; ++i) {
    int k = ty + i * 8;
    tile[k][tx] = W[(size_t)(k0 + k) * 3072 + wc + tx];
  }
  __syncthreads();
#pragma unroll
  for (int i = 0; i < 4; ++i) {
    int n = ty + i * 8;
    Wt[(size_t)(n0 + n) * 1024 + k0 + tx] = (_Float16)tile[tx][n];
  }
}

// ---------------------------------------------------------------------------
// Kernel C (v3): Q/K projection GEMM. BM=128, BN=64, BK=64; 1024 blocks
// (4/CU). Conflict-free LDS: 128-B rows (8 x 16B granules), granule s of row
// r stored at slot s^(r&7) via pre-swizzled global_load_lds source; fragment
// reads apply the same XOR (measured 0 conflicts in the attn kernel).
// XCD-bijective id map: each XCD owns 4 n-panels (B reuse in its L2).
// ---------------------------------------------------------------------------
__global__ __launch_bounds__(256, 4) void qk_gemm_kernel(const _Float16* __restrict__ X16,
                                                         const _Float16* __restrict__ Wt,
                                                         const float* __restrict__ bias,
                                                         _Float16* __restrict__ Qh,
                                                         _Float16* __restrict__ Kh) {
  __shared__ _Float16 As[128 * 64];  // 16 KB
  __shared__ _Float16 Bs[64 * 64];   // 8 KB
  int id = blockIdx.x;
  int xcd = id & 7;
  int rest = id >> 3;
  int n0 = (xcd * 4 + (rest & 3)) * 64;  // bijective: id = xcd + 8*(n_sub + 4*m_i)
  int m0 = (rest >> 2) * 128;
  int t = threadIdx.x;
  int l = t & 63;
  int wv = t >> 6;
  int wm = wv >> 1, wn = wv & 1;
  int cl = l & 15, hi = l >> 4;
  float4v acc[4][2] = {};
  for (int k0 = 0; k0 < 1024; k0 += 64) {
    // stage A: 128 rows x 128 B, granule-swizzled source
#pragma unroll
    for (int c = 0; c < 4; ++c) {
      int gi = (wv * 4 + c) * 64 + l;
      int r_ = gi >> 3, s_ = gi & 7;
      gll16(X16 + (size_t)(m0 + r_) * 1024 + k0 + 8 * (s_ ^ (r_ & 7)), &As[(wv * 4 + c) * 512]);
    }
    // stage B: 64 rows x 128 B
#pragma unroll
    for (int c = 0; c < 2; ++c) {
      int gi = (wv * 2 + c) * 64 + l;
      int r_ = gi >> 3, s_ = gi & 7;
      gll16(Wt + (size_t)(n0 + r_) * 1024 + k0 + 8 * (s_ ^ (r_ & 7)), &Bs[(wv * 2 + c) * 512]);
    }
    __syncthreads();
#pragma unroll
    for (int kh = 0; kh < 2; ++kh) {
      int g = kh * 4 + hi;  // logical granule = k/8
      half8v a[4], b[2];
#pragma unroll
      for (int mt = 0; mt < 4; ++mt) {
        int row = wm * 64 + mt * 16 + cl;
        a[mt] = *(const half8v*)(&As[row * 64 + 8 * (g ^ (row & 7))]);
      }
#pragma unroll
      for (int nt = 0; nt < 2; ++nt) {
        int row = wn * 32 + nt * 16 + cl;
        b[nt] = *(const half8v*)(&Bs[row * 64 + 8 * (g ^ (row & 7))]);
      }
#pragma unroll
      for (int mt = 0; mt < 4; ++mt)
#pragma unroll
        for (int nt = 0; nt < 2; ++nt)
          acc[mt][nt] = __builtin_amdgcn_mfma_f32_16x16x32_f16(a[mt], b[nt], acc[mt][nt], 0, 0, 0);
    }
    __syncthreads();
  }
#pragma unroll
  for (int mt = 0; mt < 4; ++mt) {
#pragma unroll
    for (int nt = 0; nt < 2; ++nt) {
      int n_g = n0 + wn * 32 + nt * 16 + cl;
      int hh = n_g >> 7, rr = n_g & 127;
      float bv = bias[hh * 192 + rr];
      _Float16* dstbase = (rr < 64) ? Qh : Kh;
      int d = rr & 63;
#pragma unroll
      for (int r = 0; r < 4; ++r) {
        int row_g = m0 + wm * 64 + mt * 16 + hi * 4 + r;
        int bb = row_g >> 11, lr = row_g & 2047;
        dstbase[(((size_t)bb * NH + hh) * L_SEQ + lr) * DKV + d] = (_Float16)(acc[mt][nt][r] + bv);
      }
    }
  }
}

// ---------------------------------------------------------------------------
// Kernel D (v6): S = Q K^T / 8, softmax over j, write [B][H][L][L] fp32.
// LDS-staged K (global_load_lds dbuf, XOR-swizzled granules), 128-j steps,
// dual-orientation 32x32x16 MFMA passes, normalization folded into exponent,
// nontemporal direct line stores.  (unchanged from round 6)
// ---------------------------------------------------------------------------
__global__ __launch_bounds__(256, 4) void attn_softmax_kernel(const _Float16* __restrict__ Qh,
                                                              const _Float16* __restrict__ Kh,
                                                              float* __restrict__ out) {
  __shared__ _Float16 Ks[2][128 * 64];  // 32 KB dbuf, granule-swizzled rows
  __shared__ float sums[4][32];
  int id = blockIdx.x;
  int xcd = id & 7;
  int rest = id >> 3;
  int rb = rest & 31;
  int bh = ((rest >> 5) << 3) + xcd;  // bijective XCD swizzle
  int t = threadIdx.x;
  int l = t & 63;
  int wv = t >> 6;
  int lj = l & 31;   // 32-lane index (q-col in pass1 / j-col in pass2)
  int hk = l >> 5;   // k-half
  int qh = wv & 1;   // q-half owned by this wave
  int jh = wv >> 1;  // j-half of each 128-step
  int qbase = rb * 64;
  const _Float16* Qb = Qh + ((size_t)bh * L_SEQ + qbase) * DKV;
  const _Float16* Kb = Kh + (size_t)bh * L_SEQ * DKV;
  const float SC = 0.18033688011112042f;  // log2(e)/sqrt(64)

  half8v bq[4];
#pragma unroll
  for (int ks = 0; ks < 4; ++ks)
    bq[ks] = *(const half8v*)(Qb + (size_t)(qh * 32 + lj) * DKV + ks * 16 + hk * 8);

#define STAGE(bufi, j0)                                                     \
  {                                                                         \
    _Pragma("unroll") for (int c = 0; c < 4; ++c) {                         \
      int gi = (wv * 4 + c) * 64 + l;                                       \
      int r_ = gi >> 3, s_ = gi & 7;                                        \
      gll16(Kb + (size_t)((j0) + r_) * DKV + 8 * (s_ ^ (r_ & 7)),           \
            &Ks[bufi][(wv * 4 + c) * 512]);                                 \
    }                                                                       \
  }

  // ---- Pass 1: row sums.  mfma(A=K, B=Q): D col = q (lj), rows = j ----
  float lsum = 0.f;
  int buf = 0;
  STAGE(0, 0);
  __syncthreads();
  for (int s = 0; s < 16; ++s) {
    if (s + 1 < 16) STAGE(buf ^ 1, (s + 1) * 128);
#pragma unroll
    for (int q2 = 0; q2 < 2; ++q2) {
      int jq = jh * 2 + q2;
      int krow = jq * 32 + lj;
      half8v bk[4];
#pragma unroll
      for (int ks = 0; ks < 4; ++ks)
        bk[ks] = *(const half8v*)(&Ks[buf][krow * 64 + 8 * ((2 * ks + hk) ^ (krow & 7))]);
      float16v acc = {};
#pragma unroll
      for (int ks = 0; ks < 4; ++ks)
        acc = __builtin_amdgcn_mfma_f32_32x32x16_f16(bk[ks], bq[ks], acc, 0, 0, 0);
#pragma unroll
      for (int i = 0; i < 16; ++i) lsum += __builtin_amdgcn_exp2f(acc[i] * SC);
    }
    __syncthreads();
    buf ^= 1;
  }
  lsum += __shfl_xor(lsum, 32);
  if (l < 32) sums[wv][lj] = lsum;
  __syncthreads();

  float cc[16];
#pragma unroll
  for (int i = 0; i < 16; ++i) {
    int qo = (i & 3) + 8 * (i >> 2) + 4 * hk;
    cc[i] = -__log2f(sums[qh][qo] + sums[qh + 2][qo]);
  }

  // ---- Pass 2: recompute, mfma(A=Q, B=K): D col = j (lj), rows = q ----
  size_t orow0 = ((size_t)bh * L_SEQ + qbase + qh * 32) * L_SEQ;
  STAGE(0, 0);
  __syncthreads();
  buf = 0;
  for (int s = 0; s < 16; ++s) {
    if (s + 1 < 16) STAGE(buf ^ 1, (s + 1) * 128);
#pragma unroll
    for (int q2 = 0; q2 < 2; ++q2) {
      int jq = jh * 2 + q2;
      int krow = jq * 32 + lj;
      half8v bk[4];
#pragma unroll
      for (int ks = 0; ks < 4; ++ks)
        bk[ks] = *(const half8v*)(&Ks[buf][krow * 64 + 8 * ((2 * ks + hk) ^ (krow & 7))]);
      float16v acc = {};
#pragma unroll
      for (int ks = 0; ks < 4; ++ks)
        acc = __builtin_amdgcn_mfma_f32_32x32x16_f16(bq[ks], bk[ks], acc, 0, 0, 0);
      size_t col = (size_t)s * 128 + jq * 32 + lj;
#pragma unroll
      for (int i = 0; i < 16; ++i) {
        float p = __builtin_amdgcn_exp2f(acc[i] * SC + cc[i]);
        int qo = (i & 3) + 8 * (i >> 2) + 4 * hk;
        __builtin_nontemporal_store(p, out + orow0 + (size_t)qo * L_SEQ + col);
      }
    }
    __syncthreads();
    buf ^= 1;
  }
#undef STAGE
}

// ---------------------------------------------------------------------------
extern "C" void kernel_launch(void* const* d_in, const int* in_sizes, int n_in,
                              void* d_out, int out_size, void* d_ws, size_t ws_size,
                              hipStream_t stream) {
  const float* X = (const float*)d_in[0];
  const float* W = (const float*)d_in[1];
  const float* bias = (const float*)d_in[2];
  float* out = (float*)d_out;
  char* ws = (char*)d_ws;
  _Float16* Wt = (_Float16*)ws;                       // 4 MB
  _Float16* Qh = (_Float16*)(ws + (4ull << 20));      // 8 MB
  _Float16* Kh = (_Float16*)(ws + (12ull << 20));     // 8 MB
  _Float16* X16 = (_Float16*)(ws + (20ull << 20));    // 8 MB (total 28 MB)

  xcast_kernel<<<2048, 256, 0, stream>>>(X, X16);
  wpack_kernel<<<dim3(64, 32), 256, 0, stream>>>(W, Wt);
  qk_gemm_kernel<<<1024, 256, 0, stream>>>(X16, Wt, bias, Qh, Kh);
  attn_softmax_kernel<<<1024, 256, 0, stream>>>(Qh, Kh, out);
}